// Round 8
// baseline (218.224 us; speedup 1.0000x reference)
//
#include <hip/hip_runtime.h>
#include <hip/hip_bf16.h>

// Problem constants: B=8, H=W=64, T=4096, C=256
#define TB 8
#define TT 4096
#define TC 256
#define NC2 128   // chunks along T
#define CL2 32    // chunk length

typedef _Float16 half8 __attribute__((ext_vector_type(8)));
typedef _Float16 half4v __attribute__((ext_vector_type(4)));
typedef float floatx4 __attribute__((ext_vector_type(4)));

#define GLDS16(g, l) __builtin_amdgcn_global_load_lds( \
    (const __attribute__((address_space(1))) void*)(g), \
    (__attribute__((address_space(3))) void*)(l), 16, 0, 0)

// ------- prep: sobel edge gate + x hi/lo split planes + W -> f16 -------------
__global__ __launch_bounds__(256) void prep(
    const float* __restrict__ x,
    const float* __restrict__ Wk, const float* __restrict__ Wv,
    const float* __restrict__ Wr, const float* __restrict__ Wo,
    _Float16* __restrict__ Xh, _Float16* __restrict__ Xl,
    _Float16* __restrict__ Wf, float* __restrict__ edge)
{
    if (blockIdx.x >= TB * TT) {
        int t4 = (blockIdx.x - TB * TT) * 256 + threadIdx.x;
        int f = t4 * 4;
        int wsel = f >> 16;
        int i = f & 65535;
        const float* src = (wsel == 0) ? Wk : (wsel == 1) ? Wv :
                           (wsel == 2) ? Wr : Wo;
        float4 v = *(const float4*)(src + i);
        half4v h;
        h.x = (_Float16)v.x; h.y = (_Float16)v.y;
        h.z = (_Float16)v.z; h.w = (_Float16)v.w;
        *(half4v*)(Wf + (size_t)wsel * 65536 + i) = h;
        return;
    }
    int t = blockIdx.x & (TT - 1);
    int b = blockIdx.x >> 12;
    int h = t >> 6, w = t & 63;
    int c = threadIdx.x;

    float n[3][3];
    #pragma unroll
    for (int dh = 0; dh < 3; dh++) {
        int hh = h + dh - 1;
        #pragma unroll
        for (int dw = 0; dw < 3; dw++) {
            int ww = w + dw - 1;
            float val = 0.f;
            if (hh >= 0 && hh < 64 && ww >= 0 && ww < 64)
                val = x[((size_t)(b * TT + (hh << 6) + ww)) * TC + c];
            n[dh][dw] = val;
        }
    }
    float xc = n[1][1];
    _Float16 hi = (_Float16)xc;
    _Float16 lo = (_Float16)(xc - (float)hi);
    size_t mi = (size_t)(b * TT + t) * TC + c;
    Xh[mi] = hi;
    Xl[mi] = lo;

    float gx = (n[0][2] - n[0][0]) + 2.f * (n[1][2] - n[1][0]) + (n[2][2] - n[2][0]);
    float gy = (n[2][0] + 2.f * n[2][1] + n[2][2]) - (n[0][0] + 2.f * n[0][1] + n[0][2]);
    float mag = sqrtf(gx * gx + gy * gy + 1e-8f);

    #pragma unroll
    for (int off = 32; off > 0; off >>= 1) mag += __shfl_down(mag, off, 64);
    __shared__ float part[4];
    if ((threadIdx.x & 63) == 0) part[threadIdx.x >> 6] = mag;
    __syncthreads();
    if (threadIdx.x == 0) {
        float s = part[0] + part[1] + part[2] + part[3];
        edge[blockIdx.x] = 1.f / (1.f + __expf(-s * (1.f / 256.f)));
    }
}

// ------- MFMA GEMM1: C[m,n] = (Xh+Xl)[m,:] . W[n,:], tile 128x256, K=256 ----
// r5/r7-proven geometry: 4 waves of 64x128, (256,2), 32 KB LDS.
// op: 1=f16 sigmoid(+edge), 2=f16 exp, 3=f16 plain
__global__ __launch_bounds__(256, 2) void gemm_split(
    const _Float16* __restrict__ Ah_g, const _Float16* __restrict__ Al_g,
    const _Float16* __restrict__ W0, const _Float16* __restrict__ W1,
    const _Float16* __restrict__ W2p,
    void* __restrict__ C0, void* __restrict__ C1, void* __restrict__ C2,
    const float* __restrict__ edgep, int ops)
{
    __shared__ __align__(16) _Float16 smem[16384];   // 32 KB
    _Float16* Ah = smem;            // [128][32]
    _Float16* Al = smem + 4096;     // [128][32]
    _Float16* Bs = smem + 8192;     // [256][32]

    int wsel = blockIdx.y;
    const _Float16* W = (wsel == 0) ? W0 : (wsel == 1) ? W1 : W2p;
    void* Cc          = (wsel == 0) ? C0 : (wsel == 1) ? C1 : C2;
    int op = (ops >> (2 * wsel)) & 3;
    int row0 = blockIdx.x * 128;

    int tid = threadIdx.x;
    int lane = tid & 63;
    int wv = tid >> 6;
    int qm = (wv >> 1) * 64;
    int qn = (wv & 1) * 128;

    floatx4 acc[4][8];
    #pragma unroll
    for (int i = 0; i < 4; i++)
        #pragma unroll
        for (int j = 0; j < 8; j++)
            acc[i][j] = (floatx4){0.f, 0.f, 0.f, 0.f};

    for (int kb = 0; kb < 256; kb += 32) {
        __syncthreads();
        #pragma unroll
        for (int r = 0; r < 2; r++) {
            int q = r * 256 + tid;           // A segs: 512 of 16B per plane
            int row = q >> 2;
            int s = q & 3;
            int g = (s - row - (row >> 2)) & 3;   // bank-rotation inverse
            size_t goff = (size_t)(row0 + row) * TC + kb + g * 8;
            GLDS16(Ah_g + goff, &Ah[q * 8]);
            GLDS16(Al_g + goff, &Al[q * 8]);
        }
        #pragma unroll
        for (int r = 0; r < 4; r++) {
            int q = r * 256 + tid;           // B segs: 1024 of 16B
            int row = q >> 2, s = q & 3;
            int g = (s - row - (row >> 2)) & 3;
            GLDS16(W + (size_t)row * TC + kb + g * 8, &Bs[q * 8]);
        }
        __syncthreads();
        int sl = lane >> 4;
        half8 ah[4], al[4], b[8];
        #pragma unroll
        for (int i = 0; i < 4; i++) {
            int ra = qm + i * 16 + (lane & 15);
            int sa = (sl + ra + (ra >> 2)) & 3;
            ah[i] = *(const half8*)&Ah[ra * 32 + sa * 8];
            al[i] = *(const half8*)&Al[ra * 32 + sa * 8];
        }
        #pragma unroll
        for (int j = 0; j < 8; j++) {
            int rb = qn + j * 16 + (lane & 15);
            int sb = (sl + rb + (rb >> 2)) & 3;
            b[j] = *(const half8*)&Bs[rb * 32 + sb * 8];
        }
        #pragma unroll
        for (int i = 0; i < 4; i++)
            #pragma unroll
            for (int j = 0; j < 8; j++) {
                acc[i][j] = __builtin_amdgcn_mfma_f32_16x16x32_f16(
                    ah[i], b[j], acc[i][j], 0, 0, 0);
                acc[i][j] = __builtin_amdgcn_mfma_f32_16x16x32_f16(
                    al[i], b[j], acc[i][j], 0, 0, 0);
            }
    }

    // D mapping (16x16): row m = (lane>>4)*4 + reg, col n = lane&15
    int mr0 = (lane >> 4) * 4;
    int nc = lane & 15;
    #pragma unroll
    for (int i = 0; i < 4; i++) {
        #pragma unroll
        for (int r = 0; r < 4; r++) {
            int m = row0 + qm + i * 16 + mr0 + r;
            _Float16* crow = (_Float16*)Cc + (size_t)m * TC + qn + nc;
            float ev = (op == 1) ? edgep[m] : 0.f;
            #pragma unroll
            for (int j = 0; j < 8; j++) {
                float vv = acc[i][j][r];
                if (op == 1) vv = 1.f / (1.f + __expf(-vv)) + ev;
                else if (op == 2) vv = __expf(vv);
                crow[j * 16] = (_Float16)vv;
            }
        }
    }
}

// ------- MFMA GEMM2: out[m,n] = (Yh+Yl)[m,:] . Wo[n,:], tile 128x128 --------
// grid (256, 2): col0 = y*128 -> 512 blocks = 2/CU for barrier overlap.
__global__ __launch_bounds__(256, 2) void gemm_n128(
    const _Float16* __restrict__ Ah_g, const _Float16* __restrict__ Al_g,
    const _Float16* __restrict__ W, float* __restrict__ C)
{
    __shared__ __align__(16) _Float16 smem[12288];   // 24 KB
    _Float16* Ah = smem;            // [128][32]
    _Float16* Al = smem + 4096;     // [128][32]
    _Float16* Bs = smem + 8192;     // [128][32]

    int col0 = (blockIdx.y & 1) * 128;
    int row0 = blockIdx.x * 128;
    const _Float16* Bg = W + (size_t)col0 * TC;

    int tid = threadIdx.x;
    int lane = tid & 63;
    int wv = tid >> 6;
    int qm = (wv >> 1) * 64;
    int qn = (wv & 1) * 64;

    floatx4 acc[4][4];
    #pragma unroll
    for (int i = 0; i < 4; i++)
        #pragma unroll
        for (int j = 0; j < 4; j++)
            acc[i][j] = (floatx4){0.f, 0.f, 0.f, 0.f};

    for (int kb = 0; kb < 256; kb += 32) {
        __syncthreads();
        #pragma unroll
        for (int r = 0; r < 2; r++) {
            int q = r * 256 + tid;           // 512 segs of 16B per matrix
            int row = q >> 2;
            int s = q & 3;
            int g = (s - row - (row >> 2)) & 3;
            size_t goff = (size_t)(row0 + row) * TC + kb + g * 8;
            GLDS16(Ah_g + goff, &Ah[q * 8]);
            GLDS16(Al_g + goff, &Al[q * 8]);
            GLDS16(Bg + (size_t)row * TC + kb + g * 8, &Bs[q * 8]);
        }
        __syncthreads();
        int sl = lane >> 4;
        half8 ah[4], al[4], b[4];
        #pragma unroll
        for (int i = 0; i < 4; i++) {
            int ra = qm + i * 16 + (lane & 15);
            int sa = (sl + ra + (ra >> 2)) & 3;
            ah[i] = *(const half8*)&Ah[ra * 32 + sa * 8];
            al[i] = *(const half8*)&Al[ra * 32 + sa * 8];
        }
        #pragma unroll
        for (int j = 0; j < 4; j++) {
            int rb = qn + j * 16 + (lane & 15);
            int sb = (sl + rb + (rb >> 2)) & 3;
            b[j] = *(const half8*)&Bs[rb * 32 + sb * 8];
        }
        #pragma unroll
        for (int i = 0; i < 4; i++)
            #pragma unroll
            for (int j = 0; j < 4; j++) {
                acc[i][j] = __builtin_amdgcn_mfma_f32_16x16x32_f16(
                    ah[i], b[j], acc[i][j], 0, 0, 0);
                acc[i][j] = __builtin_amdgcn_mfma_f32_16x16x32_f16(
                    al[i], b[j], acc[i][j], 0, 0, 0);
            }
    }

    int mr0 = (lane >> 4) * 4;
    int nc = lane & 15;
    #pragma unroll
    for (int i = 0; i < 4; i++) {
        #pragma unroll
        for (int r = 0; r < 4; r++) {
            int m = row0 + qm + i * 16 + mr0 + r;
            float* crow = C + (size_t)m * TC + col0 + qn + nc;
            #pragma unroll
            for (int j = 0; j < 4; j++)
                crow[j * 16] = acc[i][j][r];
        }
    }
}

// ------- WKV phase A: per-chunk local sums (ek, v f16 inputs) ----------------
__global__ __launch_bounds__(256) void wkv_chunk_sums(
    const _Float16* __restrict__ ekp, const _Float16* __restrict__ vp,
    const float* __restrict__ decay,
    float* __restrict__ SaF, float* __restrict__ SbF,
    float* __restrict__ RaB, float* __restrict__ RbB)
{
    int tid = blockIdx.x * 256 + threadIdx.x;   // B*NC2*C
    int c = tid & 255;
    int j = (tid >> 8) & (NC2 - 1);
    int b = tid >> 15;
    float w = decay[c] * (1.f / (float)TT);
    float d = __expf(-w);
    size_t base = ((size_t)(b * TT + j * CL2)) * TC + c;
    float Sa = 0.f, Sb = 0.f, Ra = 0.f, Rb = 0.f, pw = 1.f;
    #pragma unroll
    for (int i = 0; i < CL2; i++) {
        float ek = (float)ekp[base + (size_t)i * TC];
        float vv = (float)vp[base + (size_t)i * TC];
        float ekv = ek * vv;
        Sa = fmaf(d, Sa, ekv);
        Sb = fmaf(d, Sb, ek);
        Ra = fmaf(pw, ekv, Ra);
        Rb = fmaf(pw, ek, Rb);
        pw *= d;
    }
    int idx = (b * NC2 + j) * TC + c;
    SaF[idx] = Sa; SbF[idx] = Sb; RaB[idx] = Ra; RbB[idx] = Rb;
}

// ------- WKV phase B: Kogge-Stone wave scan over 128 chunks ------------------
// ONE WAVE per (b,c): 2048 waves -> 512 blocks of 256 threads.
__global__ __launch_bounds__(256) void wkv_carries(
    const float* __restrict__ SaF, const float* __restrict__ SbF,
    const float* __restrict__ RaB, const float* __restrict__ RbB,
    const float* __restrict__ decay,
    float* __restrict__ CfA, float* __restrict__ CfB,
    float* __restrict__ CbA, float* __restrict__ CbB)
{
    int gw = (blockIdx.x * 256 + threadIdx.x) >> 6;   // 0..2047
    int lane = threadIdx.x & 63;
    int c = gw & 255, b = gw >> 8;
    float w = decay[c] * (1.f / (float)TT);
    float D = __expf(-(float)CL2 * w);
    int base = b * NC2 * TC + c;
    int j0 = 2 * lane, j1 = 2 * lane + 1;
    int r0 = NC2 - 1 - j0, r1 = NC2 - 2 - j0;

    float sa0 = SaF[base + j0 * TC], sa1 = SaF[base + j1 * TC];
    float sb0 = SbF[base + j0 * TC], sb1 = SbF[base + j1 * TC];
    float qa0 = RaB[base + r0 * TC], qa1 = RaB[base + r1 * TC];
    float qb0 = RbB[base + r0 * TC], qb1 = RbB[base + r1 * TC];

    float pa = fmaf(D, sa0, sa1), pb = fmaf(D, sb0, sb1);
    float ra = fmaf(D, qa0, qa1), rb = fmaf(D, qb0, qb1);

    float dp = D * D;
    #pragma unroll
    for (int off = 1; off < 64; off <<= 1) {
        float ta = __shfl_up(pa, off, 64);
        float tb = __shfl_up(pb, off, 64);
        float ua = __shfl_up(ra, off, 64);
        float ub = __shfl_up(rb, off, 64);
        if (lane >= off) {
            pa = fmaf(dp, ta, pa); pb = fmaf(dp, tb, pb);
            ra = fmaf(dp, ua, ra); rb = fmaf(dp, ub, rb);
        }
        dp = dp * dp;
    }
    float ppa = __shfl_up(pa, 1, 64);
    float ppb = __shfl_up(pb, 1, 64);
    float pra = __shfl_up(ra, 1, 64);
    float prb = __shfl_up(rb, 1, 64);
    if (lane == 0) { ppa = 0.f; ppb = 0.f; pra = 0.f; prb = 0.f; }

    CfA[base + j0 * TC] = ppa;
    CfA[base + j1 * TC] = fmaf(D, ppa, sa0);
    CfB[base + j0 * TC] = ppb;
    CfB[base + j1 * TC] = fmaf(D, ppb, sb0);
    CbA[base + r0 * TC] = pra;
    CbA[base + r1 * TC] = fmaf(D, pra, qa0);
    CbB[base + r0 * TC] = prb;
    CbB[base + r1 * TC] = fmaf(D, prb, qb0);
}

// ------- WKV phase C: combine + gate -> Yh/Yl planes -------------------------
// Backward pass caches ek and v (f16) in LDS (32 KB); forward pass reads them
// back (same thread, no barrier). sr input already includes the edge gate.
__global__ __launch_bounds__(256) void wkv_combine(
    const _Float16* __restrict__ ekp, const _Float16* __restrict__ vp,
    const _Float16* __restrict__ srp,
    const float* __restrict__ decay, const float* __restrict__ first,
    const float* __restrict__ CfA, const float* __restrict__ CfB,
    const float* __restrict__ CbA, const float* __restrict__ CbB,
    _Float16* __restrict__ Yh, _Float16* __restrict__ Yl)
{
    __shared__ _Float16 ekL[CL2 * 256];   // 16 KB
    __shared__ _Float16 vL[CL2 * 256];    // 16 KB
    int bid = blockIdx.x;            // B*NC2 = 1024
    int j = bid & (NC2 - 1);
    int b = bid >> 7;
    int c = threadIdx.x;

    float w = decay[c] * (1.f / (float)TT);
    float d = __expf(-w);
    float eu = __expf(first[c] * (1.f / (float)TT));
    int cidx = (b * NC2 + j) * TC + c;
    size_t base = ((size_t)(b * TT + j * CL2)) * TC + c;

    float abArr[CL2], bbArr[CL2];
    float ab = CbA[cidx], bb = CbB[cidx];
    #pragma unroll
    for (int i = CL2 - 1; i >= 0; i--) {
        _Float16 ekh16 = ekp[base + (size_t)i * TC];
        _Float16 vh16 = vp[base + (size_t)i * TC];
        float ek = (float)ekh16;
        float vv = (float)vh16;
        float ekv = ek * vv;
        ekL[i * 256 + c] = ekh16;
        vL[i * 256 + c] = vh16;
        abArr[i] = ab; bbArr[i] = bb;
        ab = fmaf(d, ab, ekv);
        bb = fmaf(d, bb, ek);
    }
    float af = CfA[cidx], bf = CfB[cidx];
    #pragma unroll
    for (int i = 0; i < CL2; i++) {
        size_t idx = base + (size_t)i * TC;
        float ek = (float)ekL[i * 256 + c];
        float vv = (float)vL[i * 256 + c];
        float ekv = ek * vv;
        float srv = (float)srp[idx];     // sigmoid(r) + edge (from gemm1)
        float num = fmaf(eu, ekv, af + abArr[i]);
        float den = fmaf(eu, ek, bf + bbArr[i]);
        float yv = srv * (num / den);
        _Float16 yh = (_Float16)yv;
        _Float16 yl = (_Float16)(yv - (float)yh);
        Yh[idx] = yh;
        Yl[idx] = yl;
        af = fmaf(d, af, ekv);
        bf = fmaf(d, bf, ek);
    }
}

// -----------------------------------------------------------------------------
extern "C" void kernel_launch(void* const* d_in, const int* in_sizes, int n_in,
                              void* d_out, int out_size, void* d_ws, size_t ws_size,
                              hipStream_t stream)
{
    const float* x      = (const float*)d_in[0];
    const float* Wk     = (const float*)d_in[1];
    const float* Wv     = (const float*)d_in[2];
    const float* Wr     = (const float*)d_in[3];
    const float* Wo     = (const float*)d_in[4];
    const float* sdecay = (const float*)d_in[5];
    const float* sfirst = (const float*)d_in[6];
    float* out = (float*)d_out;

    char* ws = (char*)d_ws;
    size_t off = 0;
    const size_t PH = (size_t)TB * TT * TC * sizeof(_Float16);   // 16 MiB plane
    _Float16* Xh  = (_Float16*)(ws + off); off += PH;   // reused as Yh
    _Float16* Xl  = (_Float16*)(ws + off); off += PH;   // reused as Yl
    _Float16* ekh = (_Float16*)(ws + off); off += PH;
    _Float16* vbuf  = (_Float16*)(ws + off); off += PH;
    _Float16* srbuf = (_Float16*)(ws + off); off += PH;
    _Float16* Wf = (_Float16*)(ws + off); off += (size_t)4 * TC * TC * sizeof(_Float16);
    float* edge  = (float*)(ws + off); off += (size_t)TB * TT * sizeof(float);
    const size_t CHB = (size_t)TB * NC2 * TC * sizeof(float);    // 1 MiB each
    float* SaF = (float*)(ws + off); off += CHB;
    float* SbF = (float*)(ws + off); off += CHB;
    float* RaB = (float*)(ws + off); off += CHB;
    float* RbB = (float*)(ws + off); off += CHB;
    float* CfA = (float*)(ws + off); off += CHB;
    float* CfB = (float*)(ws + off); off += CHB;
    float* CbA = (float*)(ws + off); off += CHB;
    float* CbB = (float*)(ws + off); off += CHB;

    _Float16* WfK = Wf;
    _Float16* WfV = Wf + (size_t)TC * TC;
    _Float16* WfR = Wf + (size_t)2 * TC * TC;
    _Float16* WfO = Wf + (size_t)3 * TC * TC;

    // 1) sobel + x split + W convert
    prep<<<TB * TT + 256, 256, 0, stream>>>(x, Wk, Wv, Wr, Wo, Xh, Xl, Wf, edge);

    // 2) ek = exp(x@Wk^T) f16, v f16, sr = sigmoid(x@Wr^T)+edge f16
    int ops1 = 2 | (3 << 2) | (1 << 4);
    gemm_split<<<dim3((TB * TT) / 128, 3), 256, 0, stream>>>(
        Xh, Xl, WfK, WfV, WfR, ekh, vbuf, srbuf, edge, ops1);

    // 3) chunk-local sums
    wkv_chunk_sums<<<(TB * NC2 * TC) / 256, 256, 0, stream>>>(
        ekh, vbuf, sdecay, SaF, SbF, RaB, RbB);
    // 4) carries: one wave per (b,c) -> 512 blocks
    wkv_carries<<<(TB * TC * 64) / 256, 256, 0, stream>>>(
        SaF, SbF, RaB, RbB, sdecay, CfA, CfB, CbA, CbB);
    // 5) combine -> Yh/Yl (reuse Xh/Xl)
    wkv_combine<<<TB * NC2, 256, 0, stream>>>(
        ekh, vbuf, srbuf, sdecay, sfirst, CfA, CfB, CbA, CbB, Xh, Xl);

    // 6) out = y @ Wo^T (fp32 out), 128x128 tiles -> 512 blocks
    gemm_n128<<<dim3((TB * TT) / 128, 2), 256, 0, stream>>>(
        Xh, Xl, WfO, out);
}